// Round 6
// baseline (74.752 us; speedup 1.0000x reference)
//
#include <hip/hip_runtime.h>

#define N_NODES 4096
#define DMODEL  256
#define NHEAD   8
#define HDIM    32
#define LN_EPS  1e-5f
#define LPG     16   // lanes per (node,head) group in attn
#define MAXDEG  64   // padded-CSR row capacity (Poisson λ≈17, P(>64)≈0)

typedef __attribute__((ext_vector_type(8))) short short8;
typedef __attribute__((ext_vector_type(4))) float f32x4;

__device__ __forceinline__ unsigned short f2bf(float f) {
  unsigned int x = __float_as_uint(f);
  x += 0x7fffu + ((x >> 16) & 1u);   // round-to-nearest-even
  return (unsigned short)(x >> 16);
}

// --- prep: sections by blockIdx.x ---
//  [0,256)        : stage weights Wt[m][n][k] = bf16(W[m][k][n]) via LDS tile
//  [256,256+EB)   : clear touched bitmap words (edge-driven)
//  [256+EB, +16)  : clear cnt[4096]
__global__ __launch_bounds__(256) void prep_kernel(
    const float* __restrict__ w0, const float* __restrict__ w1,
    const float* __restrict__ w2, const float* __restrict__ w3,
    unsigned short* __restrict__ wt,
    const int* __restrict__ e0, const int* __restrict__ e1, int ne, int eb,
    unsigned int* __restrict__ bits, int* __restrict__ cnt) {
  __shared__ float t[32][33];
  int bid = blockIdx.x, tid = threadIdx.x;
  if (bid < 256) {
    int kbi = bid & 7, nbi = (bid >> 3) & 7, m = bid >> 6;
    const float* w = (m == 0) ? w0 : (m == 1) ? w1 : (m == 2) ? w2 : w3;
    int tx = tid & 31, ty = tid >> 5;   // 32 x 8
    int kb = kbi * 32, nb = nbi * 32;
#pragma unroll
    for (int r = 0; r < 32; r += 8)
      t[ty + r][tx] = w[(kb + ty + r) * 256 + nb + tx];   // coalesced in n
    __syncthreads();
    unsigned short* o = wt + m * 65536;
#pragma unroll
    for (int r = 0; r < 32; r += 8)
      o[(nb + ty + r) * 256 + kb + tx] = f2bf(t[tx][ty + r]);  // coalesced in k
  } else if (bid < 256 + eb) {
    int i = (bid - 256) * 256 + tid;
    if (i < ne) {
      unsigned int bitpos = ((unsigned int)e0[i] << 12) | (unsigned int)e1[i];
      bits[bitpos >> 5] = 0u;
    }
  } else {
    cnt[(bid - 256 - eb) * 256 + tid] = 0;
  }
}

// ------ fused: QKV GEMM (768 blocks, one matrix each) + edge scatter --------
//  [0,768)    : GEMM blocks — mat = bid>>8, 16 rows x 256 cols
//  [768,768+EB): edge dedup + padded-CSR scatter
__global__ __launch_bounds__(256) void qkv_scatter(
    const float* __restrict__ x, const unsigned short* __restrict__ wt,
    const float* __restrict__ bq, const float* __restrict__ bk,
    const float* __restrict__ bv,
    const int* __restrict__ e0, const int* __restrict__ e1, int ne,
    unsigned int* __restrict__ bits, int* __restrict__ cnt,
    int* __restrict__ colidx,
    float* __restrict__ Qf, float* __restrict__ Kf, float* __restrict__ Vf) {
  int bid = blockIdx.x, tid = threadIdx.x;
  if (bid >= 768) {
    int i = (bid - 768) * 256 + tid;
    if (i < ne) {
      int s = e0[i], d = e1[i];
      unsigned int bitpos = ((unsigned int)s << 12) | (unsigned int)d;
      unsigned int word = bitpos >> 5, msk = 1u << (bitpos & 31);
      unsigned int old = atomicOr(&bits[word], msk);
      if (!(old & msk)) {
        int pos = atomicAdd(&cnt[s], 1);
        if (pos < MAXDEG) colidx[s * MAXDEG + pos] = d;
      }
    }
    return;
  }
  int mat = bid >> 8, mb = bid & 255;
  int lane = tid & 63, w = tid >> 6;
  int Mbase = mb * 16;
  int arow = lane & 15, kgrp = lane >> 4;

  short8 a[8];
  const float* ab = x + (Mbase + arow) * 256 + kgrp * 8;
#pragma unroll
  for (int kk = 0; kk < 8; ++kk) {
    float4 v0 = *reinterpret_cast<const float4*>(ab + kk * 32);
    float4 v1 = *reinterpret_cast<const float4*>(ab + kk * 32 + 4);
    short8 t;
    t[0] = (short)f2bf(v0.x); t[1] = (short)f2bf(v0.y);
    t[2] = (short)f2bf(v0.z); t[3] = (short)f2bf(v0.w);
    t[4] = (short)f2bf(v1.x); t[5] = (short)f2bf(v1.y);
    t[6] = (short)f2bf(v1.z); t[7] = (short)f2bf(v1.w);
    a[kk] = t;
  }

  const float* bias_p = (mat == 0) ? bq : (mat == 1) ? bk : bv;
  float* o = (mat == 0) ? Qf : (mat == 1) ? Kf : Vf;
  const unsigned short* wm = wt + mat * 65536;
#pragma unroll
  for (int nf = 0; nf < 4; ++nf) {
    int col = w * 64 + nf * 16 + arow;
    const unsigned short* bb = wm + col * 256 + kgrp * 8;
    f32x4 acc = {0.f, 0.f, 0.f, 0.f};
#pragma unroll
    for (int kk = 0; kk < 8; ++kk) {
      short8 b = *reinterpret_cast<const short8*>(bb + kk * 32);
      acc = __builtin_amdgcn_mfma_f32_16x16x32_bf16(a[kk], b, acc, 0, 0, 0);
    }
    float bias = bias_p[col];
#pragma unroll
    for (int r = 0; r < 4; ++r) {
      int row = Mbase + kgrp * 4 + r;
      o[row * 256 + col] = acc[r] + bias;
    }
  }
}

// -------- sparse attention: 16 lanes per (node, head) -----------------------
// Phase A: lane g computes the 32-dim dot for neighbor (base+g); group
//          online-softmax via width-16 shfl_xor reductions.
// Phase B: lane g owns output dims 2g..2g+1; V rows loaded fully coalesced
//          (16 lanes x float2 = 128B row), broadcast (c,p) in two chunks of 8.
__global__ __launch_bounds__(256) void attn_kernel(
    const float* __restrict__ Qf, const float* __restrict__ Kf,
    const float* __restrict__ Vf, const int* __restrict__ cnt,
    const int* __restrict__ colidx, unsigned short* __restrict__ att) {
  int tid = blockIdx.x * 256 + threadIdx.x;
  int grp = tid >> 4;          // (node, head) pair
  int gl  = tid & (LPG - 1);   // lane in group
  int n = grp >> 3, h = grp & 7;

  const float4* q4 = reinterpret_cast<const float4*>(Qf + n * 256 + h * 32);
  float4 q[8];
#pragma unroll
  for (int j = 0; j < 8; ++j) q[j] = q4[j];

  int deg = cnt[n]; deg = (deg > MAXDEG) ? MAXDEG : deg;
  const int* nbrs = colidx + n * MAXDEG;
  float m = -3.0e38f, l = 0.f;
  float acc0 = 0.f, acc1 = 0.f;
  const float scale = 0.17677669529663687f;  // 1/sqrt(32)

  for (int base = 0; base < deg; base += LPG) {
    int idx = base + gl;
    bool act = idx < deg;
    int c = act ? nbrs[idx] : 0;
    float s = -3.0e38f;
    if (act) {
      const float4* k4 = reinterpret_cast<const float4*>(Kf + c * 256 + h * 32);
      float d = 0.f;
#pragma unroll
      for (int j = 0; j < 8; ++j) {
        float4 kv = k4[j];
        d += q[j].x * kv.x + q[j].y * kv.y + q[j].z * kv.z + q[j].w * kv.w;
      }
      s = d * scale;
    }
    float gm = s;
#pragma unroll
    for (int off = 1; off < LPG; off <<= 1) gm = fmaxf(gm, __shfl_xor(gm, off, LPG));
    float nm = fmaxf(m, gm);
    float p = act ? __expf(s - nm) : 0.f;
    float gs = p;
#pragma unroll
    for (int off = 1; off < LPG; off <<= 1) gs += __shfl_xor(gs, off, LPG);
    float sc = __expf(m - nm);
    l = l * sc + gs;
    m = nm;
    acc0 *= sc; acc1 *= sc;

#pragma unroll
    for (int half = 0; half < 2; ++half) {
      int cj[8]; float pj[8];
#pragma unroll
      for (int j = 0; j < 8; ++j) {
        cj[j] = __shfl(c, half * 8 + j, LPG);
        pj[j] = __shfl(p, half * 8 + j, LPG);
      }
      float2 vv[8];
#pragma unroll
      for (int j = 0; j < 8; ++j)
        vv[j] = *reinterpret_cast<const float2*>(Vf + cj[j] * 256 + h * 32 + gl * 2);
#pragma unroll
      for (int j = 0; j < 8; ++j) {
        acc0 += pj[j] * vv[j].x;
        acc1 += pj[j] * vv[j].y;
      }
    }
  }
  float rl = 1.f / l;
  ushort2 o;
  o.x = f2bf(acc0 * rl);
  o.y = f2bf(acc1 * rl);
  *reinterpret_cast<ushort2*>(att + n * 256 + h * 32 + gl * 2) = o;
}

// -------- output GEMM + bias + residual + LayerNorm (fused per 16 rows) -----
__global__ __launch_bounds__(256) void out_ln_kernel(
    const unsigned short* __restrict__ att, const unsigned short* __restrict__ wot,
    const float* __restrict__ bo, const float* __restrict__ x,
    const float* __restrict__ gamma, const float* __restrict__ beta,
    float* __restrict__ out) {
  __shared__ float ylds[16][260];
  __shared__ float ps[16][17], pq[16][17];
  __shared__ float mu_s[16], ri_s[16];
  int tid = threadIdx.x, lane = tid & 63, w = tid >> 6;
  int Mbase = blockIdx.x * 16;
  int arow = lane & 15, kgrp = lane >> 4;

  short8 a[8];
  const unsigned short* ab = att + (Mbase + arow) * 256 + kgrp * 8;
#pragma unroll
  for (int kk = 0; kk < 8; ++kk)
    a[kk] = *reinterpret_cast<const short8*>(ab + kk * 32);

#pragma unroll
  for (int nf = 0; nf < 4; ++nf) {
    int col = w * 64 + nf * 16 + arow;
    const unsigned short* bb = wot + col * 256 + kgrp * 8;
    f32x4 acc = {0.f, 0.f, 0.f, 0.f};
#pragma unroll
    for (int kk = 0; kk < 8; ++kk) {
      short8 b = *reinterpret_cast<const short8*>(bb + kk * 32);
      acc = __builtin_amdgcn_mfma_f32_16x16x32_bf16(a[kk], b, acc, 0, 0, 0);
    }
    float bof = bo[col];
#pragma unroll
    for (int r = 0; r < 4; ++r) {
      int row = kgrp * 4 + r;
      float xv = x[(Mbase + row) * 256 + col];
      ylds[row][col] = acc[r] + bof + xv;
    }
  }
  __syncthreads();

  int r = tid >> 4, seg = tid & 15;
  float s = 0.f, sq = 0.f;
#pragma unroll
  for (int j = 0; j < 16; ++j) {
    float v = ylds[r][seg * 16 + j];
    s += v;
    sq += v * v;
  }
  ps[r][seg] = s;
  pq[r][seg] = sq;
  __syncthreads();
  if (tid < 16) {
    float S = 0.f, Q2 = 0.f;
#pragma unroll
    for (int c = 0; c < 16; ++c) { S += ps[tid][c]; Q2 += pq[tid][c]; }
    float mu = S * (1.f / 256.f);
    float var = Q2 * (1.f / 256.f) - mu * mu;
    mu_s[tid] = mu;
    ri_s[tid] = rsqrtf(var + LN_EPS);
  }
  __syncthreads();
  float mu = mu_s[r], ri = ri_s[r];
  float* orow = out + (Mbase + r) * 256;
#pragma unroll
  for (int j = 0; j < 16; ++j) {
    int c = seg * 16 + j;
    float v = (ylds[r][c] - mu) * ri * gamma[c] + beta[c];
    orow[c] = v;
  }
}

// ---------------------------------------------------------------------------
extern "C" void kernel_launch(void* const* d_in, const int* in_sizes, int n_in,
                              void* d_out, int out_size, void* d_ws, size_t ws_size,
                              hipStream_t stream) {
  const float* x     = (const float*)d_in[0];
  const int*   edges = (const int*)d_in[1];
  const float* Wq    = (const float*)d_in[2];
  const float* bq    = (const float*)d_in[3];
  const float* Wk    = (const float*)d_in[4];
  const float* bk    = (const float*)d_in[5];
  const float* Wv    = (const float*)d_in[6];
  const float* bv    = (const float*)d_in[7];
  const float* Wo    = (const float*)d_in[8];
  const float* bo    = (const float*)d_in[9];
  const float* gamma = (const float*)d_in[10];
  const float* beta  = (const float*)d_in[11];
  float* out = (float*)d_out;
  int NE = in_sizes[1] / 2;
  int EB = (NE + 255) / 256;

  // workspace carve (256B aligned)
  char* p = (char*)d_ws;
  auto carve = [&](size_t sz) { char* r = p; p += ((sz + 255) / 256) * 256; return r; };
  unsigned short* Wt   = (unsigned short*)carve(4 * 65536 * sizeof(unsigned short));
  float*          Qf   = (float*)carve((size_t)N_NODES * DMODEL * sizeof(float));
  float*          Kf   = (float*)carve((size_t)N_NODES * DMODEL * sizeof(float));
  float*          Vf   = (float*)carve((size_t)N_NODES * DMODEL * sizeof(float));
  unsigned short* att  = (unsigned short*)carve((size_t)N_NODES * DMODEL * sizeof(unsigned short));
  unsigned int*   bits = (unsigned int*)carve((size_t)N_NODES * N_NODES / 8);
  int*            cnt  = (int*)carve(N_NODES * sizeof(int));
  int*            colidx = (int*)carve((size_t)N_NODES * MAXDEG * sizeof(int));

  prep_kernel<<<256 + EB + 16, 256, 0, stream>>>(Wq, Wk, Wv, Wo, Wt,
                                                 edges, edges + NE, NE, EB, bits, cnt);
  qkv_scatter<<<768 + EB, 256, 0, stream>>>(x, Wt, bq, bk, bv,
                                            edges, edges + NE, NE, bits, cnt, colidx,
                                            Qf, Kf, Vf);
  attn_kernel<<<(N_NODES * NHEAD * LPG) / 256, 256, 0, stream>>>(Qf, Kf, Vf, cnt, colidx, att);
  out_ln_kernel<<<N_NODES / 16, 256, 0, stream>>>(att, Wt + 3 * 65536, bo, x, gamma, beta, out);
}

// Round 7
// 71.537 us; speedup vs baseline: 1.0449x; 1.0449x over previous
//
#include <hip/hip_runtime.h>

#define N_NODES 4096
#define DMODEL  256
#define NHEAD   8
#define HDIM    32
#define LN_EPS  1e-5f
#define LPG     16   // lanes per (node,head) group in attn
#define MAXDEG  64   // padded-CSR row capacity (Poisson λ≈17, P(>64)≈0)

typedef __attribute__((ext_vector_type(8))) short short8;
typedef __attribute__((ext_vector_type(4))) float f32x4;

__device__ __forceinline__ unsigned short f2bf(float f) {
  unsigned int x = __float_as_uint(f);
  x += 0x7fffu + ((x >> 16) & 1u);   // round-to-nearest-even
  return (unsigned short)(x >> 16);
}

// --- prep: sections by blockIdx.x ---
//  [0,256)        : stage weights Wt[m][n][k] = bf16(W[m][k][n]) via LDS tile
//  [256,256+EB)   : clear touched bitmap words (edge-driven)
//  [256+EB, +16)  : clear cnt[4096]
__global__ __launch_bounds__(256) void prep_kernel(
    const float* __restrict__ w0, const float* __restrict__ w1,
    const float* __restrict__ w2, const float* __restrict__ w3,
    unsigned short* __restrict__ wt,
    const int* __restrict__ e0, const int* __restrict__ e1, int ne, int eb,
    unsigned int* __restrict__ bits, int* __restrict__ cnt) {
  __shared__ float t[32][33];
  int bid = blockIdx.x, tid = threadIdx.x;
  if (bid < 256) {
    int kbi = bid & 7, nbi = (bid >> 3) & 7, m = bid >> 6;
    const float* w = (m == 0) ? w0 : (m == 1) ? w1 : (m == 2) ? w2 : w3;
    int tx = tid & 31, ty = tid >> 5;   // 32 x 8
    int kb = kbi * 32, nb = nbi * 32;
#pragma unroll
    for (int r = 0; r < 32; r += 8)
      t[ty + r][tx] = w[(kb + ty + r) * 256 + nb + tx];   // coalesced in n
    __syncthreads();
    unsigned short* o = wt + m * 65536;
#pragma unroll
    for (int r = 0; r < 32; r += 8)
      o[(nb + ty + r) * 256 + kb + tx] = f2bf(t[tx][ty + r]);  // coalesced in k
  } else if (bid < 256 + eb) {
    int i = (bid - 256) * 256 + tid;
    if (i < ne) {
      unsigned int bitpos = ((unsigned int)e0[i] << 12) | (unsigned int)e1[i];
      bits[bitpos >> 5] = 0u;
    }
  } else {
    cnt[(bid - 256 - eb) * 256 + tid] = 0;
  }
}

// ------ fused: QKV GEMM (shared-A, 512 thr, 8 waves) + edge scatter ---------
//  [0,256)      : GEMM blocks — 16 rows; wave w owns cols [w*32, w*32+32) of
//                 Q, K, V (x read ONCE per block, bf16-converted in-register)
//  [256,256+EB) : edge dedup + padded-CSR scatter (512 thr/block)
__global__ __launch_bounds__(512) void qkv_scatter(
    const float* __restrict__ x, const unsigned short* __restrict__ wt,
    const float* __restrict__ bq, const float* __restrict__ bk,
    const float* __restrict__ bv,
    const int* __restrict__ e0, const int* __restrict__ e1, int ne,
    unsigned int* __restrict__ bits, int* __restrict__ cnt,
    int* __restrict__ colidx,
    float* __restrict__ Qf, float* __restrict__ Kf, float* __restrict__ Vf) {
  int bid = blockIdx.x, tid = threadIdx.x;
  if (bid >= 256) {
    int i = (bid - 256) * 512 + tid;
    if (i < ne) {
      int s = e0[i], d = e1[i];
      unsigned int bitpos = ((unsigned int)s << 12) | (unsigned int)d;
      unsigned int word = bitpos >> 5, msk = 1u << (bitpos & 31);
      unsigned int old = atomicOr(&bits[word], msk);
      if (!(old & msk)) {
        int pos = atomicAdd(&cnt[s], 1);
        if (pos < MAXDEG) colidx[s * MAXDEG + pos] = d;
      }
    }
    return;
  }
  int lane = tid & 63, w = tid >> 6;   // 8 waves
  int Mbase = bid * 16;
  int arow = lane & 15, kgrp = lane >> 4;

  short8 a[8];
  const float* ab = x + (Mbase + arow) * 256 + kgrp * 8;
#pragma unroll
  for (int kk = 0; kk < 8; ++kk) {
    float4 v0 = *reinterpret_cast<const float4*>(ab + kk * 32);
    float4 v1 = *reinterpret_cast<const float4*>(ab + kk * 32 + 4);
    short8 t;
    t[0] = (short)f2bf(v0.x); t[1] = (short)f2bf(v0.y);
    t[2] = (short)f2bf(v0.z); t[3] = (short)f2bf(v0.w);
    t[4] = (short)f2bf(v1.x); t[5] = (short)f2bf(v1.y);
    t[6] = (short)f2bf(v1.z); t[7] = (short)f2bf(v1.w);
    a[kk] = t;
  }

#pragma unroll
  for (int mat = 0; mat < 3; ++mat) {
    const unsigned short* wm = wt + mat * 65536;
    const float* bias_p = (mat == 0) ? bq : (mat == 1) ? bk : bv;
    float* o = (mat == 0) ? Qf : (mat == 1) ? Kf : Vf;
#pragma unroll
    for (int nf = 0; nf < 2; ++nf) {
      int col = w * 32 + nf * 16 + arow;
      const unsigned short* bb = wm + col * 256 + kgrp * 8;
      f32x4 acc = {0.f, 0.f, 0.f, 0.f};
#pragma unroll
      for (int kk = 0; kk < 8; ++kk) {
        short8 b = *reinterpret_cast<const short8*>(bb + kk * 32);
        acc = __builtin_amdgcn_mfma_f32_16x16x32_bf16(a[kk], b, acc, 0, 0, 0);
      }
      float bias = bias_p[col];
#pragma unroll
      for (int r = 0; r < 4; ++r) {
        int row = Mbase + kgrp * 4 + r;
        o[row * 256 + col] = acc[r] + bias;
      }
    }
  }
}

// -------- sparse attention: 16 lanes per (node,head), SINGLE-PASS softmax ---
// All score strips computed first (independent K gathers, full MLP), then one
// group max / exp / sum, then the V pass. deg <= 64 = 4 strips of 16.
__global__ __launch_bounds__(256) void attn_kernel(
    const float* __restrict__ Qf, const float* __restrict__ Kf,
    const float* __restrict__ Vf, const int* __restrict__ cnt,
    const int* __restrict__ colidx, unsigned short* __restrict__ att) {
  int tid = blockIdx.x * 256 + threadIdx.x;
  int grp = tid >> 4;          // (node, head) pair
  int gl  = tid & (LPG - 1);   // lane in group
  int n = grp >> 3, h = grp & 7;

  const float4* q4 = reinterpret_cast<const float4*>(Qf + n * 256 + h * 32);
  float4 q[8];
#pragma unroll
  for (int j = 0; j < 8; ++j) q[j] = q4[j];

  int deg = cnt[n]; deg = (deg > MAXDEG) ? MAXDEG : deg;
  const int* nbrs = colidx + n * MAXDEG;
  const float scale = 0.17677669529663687f;  // 1/sqrt(32)

  // phase A: all strips' scores (independent loads)
  float s[4]; int c[4];
#pragma unroll
  for (int it = 0; it < 4; ++it) {
    int idx = it * LPG + gl;
    bool act = idx < deg;
    c[it] = 0; s[it] = -3.0e38f;
    if (act) {
      c[it] = nbrs[idx];
      const float4* k4 = reinterpret_cast<const float4*>(Kf + c[it] * 256 + h * 32);
      float d = 0.f;
#pragma unroll
      for (int j = 0; j < 8; ++j) {
        float4 kv = k4[j];
        d += q[j].x * kv.x + q[j].y * kv.y + q[j].z * kv.z + q[j].w * kv.w;
      }
      s[it] = d * scale;
    }
  }

  // one group-wide max
  float gm = fmaxf(fmaxf(s[0], s[1]), fmaxf(s[2], s[3]));
#pragma unroll
  for (int off = 1; off < LPG; off <<= 1) gm = fmaxf(gm, __shfl_xor(gm, off, LPG));

  // exp + one group-wide sum
  float p[4]; float l = 0.f;
#pragma unroll
  for (int it = 0; it < 4; ++it) { p[it] = __expf(s[it] - gm); l += p[it]; }
#pragma unroll
  for (int off = 1; off < LPG; off <<= 1) l += __shfl_xor(l, off, LPG);

  // phase B: V pass; lane gl owns dims 2gl..2gl+1 (coalesced 128B rows)
  float acc0 = 0.f, acc1 = 0.f;
#pragma unroll
  for (int it = 0; it < 4; ++it) {
    if (it * LPG >= deg) break;
#pragma unroll
    for (int half = 0; half < 2; ++half) {
      if (it * LPG + half * 8 >= deg) break;
      int cj[8]; float pj[8];
#pragma unroll
      for (int j = 0; j < 8; ++j) {
        cj[j] = __shfl(c[it], half * 8 + j, LPG);
        pj[j] = __shfl(p[it], half * 8 + j, LPG);
      }
      float2 vv[8];
#pragma unroll
      for (int j = 0; j < 8; ++j)
        vv[j] = *reinterpret_cast<const float2*>(Vf + cj[j] * 256 + h * 32 + gl * 2);
#pragma unroll
      for (int j = 0; j < 8; ++j) {
        acc0 += pj[j] * vv[j].x;
        acc1 += pj[j] * vv[j].y;
      }
    }
  }
  float rl = 1.f / l;
  ushort2 o;
  o.x = f2bf(acc0 * rl);
  o.y = f2bf(acc1 * rl);
  *reinterpret_cast<ushort2*>(att + n * 256 + h * 32 + gl * 2) = o;
}

// -------- output GEMM + bias + residual + LayerNorm (fused per 16 rows) -----
__global__ __launch_bounds__(256) void out_ln_kernel(
    const unsigned short* __restrict__ att, const unsigned short* __restrict__ wot,
    const float* __restrict__ bo, const float* __restrict__ x,
    const float* __restrict__ gamma, const float* __restrict__ beta,
    float* __restrict__ out) {
  __shared__ float ylds[16][260];
  __shared__ float ps[16][17], pq[16][17];
  __shared__ float mu_s[16], ri_s[16];
  int tid = threadIdx.x, lane = tid & 63, w = tid >> 6;
  int Mbase = blockIdx.x * 16;
  int arow = lane & 15, kgrp = lane >> 4;

  short8 a[8];
  const unsigned short* ab = att + (Mbase + arow) * 256 + kgrp * 8;
#pragma unroll
  for (int kk = 0; kk < 8; ++kk)
    a[kk] = *reinterpret_cast<const short8*>(ab + kk * 32);

#pragma unroll
  for (int nf = 0; nf < 4; ++nf) {
    int col = w * 64 + nf * 16 + arow;
    const unsigned short* bb = wot + col * 256 + kgrp * 8;
    f32x4 acc = {0.f, 0.f, 0.f, 0.f};
#pragma unroll
    for (int kk = 0; kk < 8; ++kk) {
      short8 b = *reinterpret_cast<const short8*>(bb + kk * 32);
      acc = __builtin_amdgcn_mfma_f32_16x16x32_bf16(a[kk], b, acc, 0, 0, 0);
    }
    float bof = bo[col];
#pragma unroll
    for (int r = 0; r < 4; ++r) {
      int row = kgrp * 4 + r;
      float xv = x[(Mbase + row) * 256 + col];
      ylds[row][col] = acc[r] + bof + xv;
    }
  }
  __syncthreads();

  int r = tid >> 4, seg = tid & 15;
  float s = 0.f, sq = 0.f;
#pragma unroll
  for (int j = 0; j < 16; ++j) {
    float v = ylds[r][seg * 16 + j];
    s += v;
    sq += v * v;
  }
  ps[r][seg] = s;
  pq[r][seg] = sq;
  __syncthreads();
  if (tid < 16) {
    float S = 0.f, Q2 = 0.f;
#pragma unroll
    for (int c = 0; c < 16; ++c) { S += ps[tid][c]; Q2 += pq[tid][c]; }
    float mu = S * (1.f / 256.f);
    float var = Q2 * (1.f / 256.f) - mu * mu;
    mu_s[tid] = mu;
    ri_s[tid] = rsqrtf(var + LN_EPS);
  }
  __syncthreads();
  float mu = mu_s[r], ri = ri_s[r];
  float* orow = out + (Mbase + r) * 256;
#pragma unroll
  for (int j = 0; j < 16; ++j) {
    int c = seg * 16 + j;
    float v = (ylds[r][c] - mu) * ri * gamma[c] + beta[c];
    orow[c] = v;
  }
}

// ---------------------------------------------------------------------------
extern "C" void kernel_launch(void* const* d_in, const int* in_sizes, int n_in,
                              void* d_out, int out_size, void* d_ws, size_t ws_size,
                              hipStream_t stream) {
  const float* x     = (const float*)d_in[0];
  const int*   edges = (const int*)d_in[1];
  const float* Wq    = (const float*)d_in[2];
  const float* bq    = (const float*)d_in[3];
  const float* Wk    = (const float*)d_in[4];
  const float* bk    = (const float*)d_in[5];
  const float* Wv    = (const float*)d_in[6];
  const float* bv    = (const float*)d_in[7];
  const float* Wo    = (const float*)d_in[8];
  const float* bo    = (const float*)d_in[9];
  const float* gamma = (const float*)d_in[10];
  const float* beta  = (const float*)d_in[11];
  float* out = (float*)d_out;
  int NE = in_sizes[1] / 2;
  int EB256 = (NE + 255) / 256;
  int EB512 = (NE + 511) / 512;

  // workspace carve (256B aligned)
  char* p = (char*)d_ws;
  auto carve = [&](size_t sz) { char* r = p; p += ((sz + 255) / 256) * 256; return r; };
  unsigned short* Wt   = (unsigned short*)carve(4 * 65536 * sizeof(unsigned short));
  float*          Qf   = (float*)carve((size_t)N_NODES * DMODEL * sizeof(float));
  float*          Kf   = (float*)carve((size_t)N_NODES * DMODEL * sizeof(float));
  float*          Vf   = (float*)carve((size_t)N_NODES * DMODEL * sizeof(float));
  unsigned short* att  = (unsigned short*)carve((size_t)N_NODES * DMODEL * sizeof(unsigned short));
  unsigned int*   bits = (unsigned int*)carve((size_t)N_NODES * N_NODES / 8);
  int*            cnt  = (int*)carve(N_NODES * sizeof(int));
  int*            colidx = (int*)carve((size_t)N_NODES * MAXDEG * sizeof(int));

  prep_kernel<<<256 + EB256 + 16, 256, 0, stream>>>(Wq, Wk, Wv, Wo, Wt,
                                                    edges, edges + NE, NE, EB256, bits, cnt);
  qkv_scatter<<<256 + EB512, 512, 0, stream>>>(x, Wt, bq, bk, bv,
                                               edges, edges + NE, NE, bits, cnt, colidx,
                                               Qf, Kf, Vf);
  attn_kernel<<<(N_NODES * NHEAD * LPG) / 256, 256, 0, stream>>>(Qf, Kf, Vf, cnt, colidx, att);
  out_ln_kernel<<<N_NODES / 16, 256, 0, stream>>>(att, Wt + 3 * 65536, bo, x, gamma, beta, out);
}